// Round 3
// baseline (602.585 us; speedup 1.0000x reference)
//
#include <hip/hip_runtime.h>

typedef unsigned short u16;
typedef unsigned int   u32;
typedef __bf16 bf16x8 __attribute__((ext_vector_type(8)));
typedef float  f32x4  __attribute__((ext_vector_type(4)));

__device__ __forceinline__ u16 f2b(float f) {
  u32 u = __builtin_bit_cast(u32, f);
  u = (u + 0x7fffu + ((u >> 16) & 1u)) >> 16;   // RNE
  return (u16)u;
}
__device__ __forceinline__ float b2f(u16 h) {
  u32 u = ((u32)h) << 16;
  return __builtin_bit_cast(float, u);
}
// Read input element idx as float, from either fp32 or bf16 source
__device__ __forceinline__ float ld_in(const void* p, size_t idx, int isf32) {
  return isf32 ? ((const float*)p)[idx] : b2f(((const u16*)p)[idx]);
}

// Constants: BS=1024, CH=3, IMG=64, K=16, NC=10, HID=1024, LAT=128
// OH=4, L=16, PD=768, M = 16384. Row-chunked; R adapts to ws_size.
#define RECON_ELEMS 12582912   // 1024*3*64*64

// ---------------------------------------------------------------------------
// dtype detector: bf16 uniform[0,1) values are u16 in [0,0x3F80], sign=0.
// fp32 low mantissa halves are random 16-bit words -> flag=1 w.p. ~1.
// ---------------------------------------------------------------------------
__global__ __launch_bounds__(256) void detect_f32(const u16* __restrict__ x,
                                                  int* __restrict__ flag) {
  __shared__ int s;
  if (threadIdx.x == 0) s = 0;
  __syncthreads();
  int bad = 0;
  for (int i = threadIdx.x; i < 2048; i += 256) {
    u16 u = x[i];
    if ((u & 0x8000u) || (u > 0x3F80u)) bad = 1;
  }
  if (bad) atomicOr(&s, 1);
  __syncthreads();
  if (threadIdx.x == 0) *flag = s;
}

// ---------------------------------------------------------------------------
// A1 chunk (R x 800 bf16): [patch(768) | c(10) | zeros(22)]
// ---------------------------------------------------------------------------
__global__ __launch_bounds__(256) void build_a1(const void* __restrict__ x,
                                                const void* __restrict__ c,
                                                u16* __restrict__ A1,
                                                int R, int rowOff,
                                                const int* __restrict__ flag) {
  int g = blockIdx.x * 256 + threadIdx.x;          // R * 100 groups of 8 cols
  if (g >= R * 100) return;
  int row = g / 100, grp = g - row * 100;
  int grow = row + rowOff;
  int b = grow >> 4, l = grow & 15, oh = l >> 2, ow = l & 3;
  int isf = *flag;
  u16* dst = &A1[(size_t)row * 800 + grp * 8];
  int col0 = grp * 8;
  if (col0 < 768) {
    int ch = col0 >> 8, kh = (col0 >> 4) & 15, kw = col0 & 15;  // kw in {0,8}
    size_t off = (size_t)b * 12288 + ch * 4096 + (oh * 16 + kh) * 64 + ow * 16 + kw;
    if (isf) {
      const float* s = (const float*)x + off;
      float4 f0 = *(const float4*)(s);
      float4 f1 = *(const float4*)(s + 4);
      dst[0] = f2b(f0.x); dst[1] = f2b(f0.y); dst[2] = f2b(f0.z); dst[3] = f2b(f0.w);
      dst[4] = f2b(f1.x); dst[5] = f2b(f1.y); dst[6] = f2b(f1.z); dst[7] = f2b(f1.w);
    } else {
      *(int4*)dst = *(const int4*)((const u16*)x + off);
    }
  } else {
#pragma unroll
    for (int t = 0; t < 8; ++t) {
      int col = col0 + t;
      dst[t] = (col < 778) ? f2b(ld_in(c, (size_t)b * 10 + (col - 768), isf)) : (u16)0;
    }
  }
}

// dst (N x Kpad) = transpose of src (Ksrc x N), zero-padded in K
__global__ __launch_bounds__(256) void transpose_pad(const void* __restrict__ src,
                                                     u16* __restrict__ dst,
                                                     int N, int Kpad, int Ksrc,
                                                     const int* __restrict__ flag) {
  int i = blockIdx.x * 256 + threadIdx.x;
  if (i >= N * Kpad) return;
  int n = i / Kpad, k = i - n * Kpad;
  int isf = *flag;
  dst[i] = (k < Ksrc) ? f2b(ld_in(src, (size_t)k * N + n, isf)) : (u16)0;
}

// A3 chunk tail cols 128..159: [c(10) | zeros(22)]
__global__ __launch_bounds__(256) void build_a3_tail(const void* __restrict__ c,
                                                     u16* __restrict__ A3,
                                                     int R, int rowOff,
                                                     const int* __restrict__ flag) {
  int i = blockIdx.x * 256 + threadIdx.x;          // R*32
  if (i >= R * 32) return;
  int row = i >> 5, col = 128 + (i & 31);
  int b = (row + rowOff) >> 4;
  int isf = *flag;
  A3[(size_t)row * 160 + col] = (col < 138) ? f2b(ld_in(c, (size_t)b * 10 + col - 128, isf)) : (u16)0;
}

// ---------------------------------------------------------------------------
// MFMA GEMM: C(R x N) = act(A(R x K) @ Bt(N x K)^T + bias)
// 128x128 tile, BK=32, 4 waves (2x2), each wave 4x4 16x16x32 MFMA tiles.
// EPI: 0 = ReLU -> bf16 outb row-major (ld=N), chunk-local rows (internal h)
//      1 = none -> f32 outf = mu_logvar_2d scatter (global rows),
//                  bf16 out1 = A3 mu part (local, ld=160)
//      2 = sigmoid -> f32 outf = recon scatter (global rows)
// ---------------------------------------------------------------------------
template <int EPI>
__global__ __launch_bounds__(256) void gemm_k(const u16* __restrict__ A,
                                              const u16* __restrict__ Bt,
                                              const void* __restrict__ bias,
                                              u16* __restrict__ outb,
                                              float* __restrict__ outf,
                                              u16* __restrict__ out1,
                                              int N, int K, int rowOff,
                                              const int* __restrict__ flag) {
  __shared__ __align__(16) u16 As[128 * 32];
  __shared__ __align__(16) u16 Bs[128 * 32];
  const int tid  = threadIdx.x;
  const int lane = tid & 63;
  const int wave = tid >> 6;
  const int wr = (wave >> 1) * 64, wc = (wave & 1) * 64;
  const int quad = lane >> 4, l16 = lane & 15;
  const int rowBase = blockIdx.y * 128;
  const int colBase = blockIdx.x * 128;

  f32x4 acc[4][4] = {};

  for (int k0 = 0; k0 < K; k0 += 32) {
    __syncthreads();
#pragma unroll
    for (int i = 0; i < 2; ++i) {
      int idx = i * 256 + tid;                   // 512 chunks of 16B each
      int r = idx >> 2, cc = (idx & 3) << 3;
      *(int4*)(&As[r * 32 + cc]) = *(const int4*)(&A[(size_t)(rowBase + r) * K + k0 + cc]);
      *(int4*)(&Bs[r * 32 + cc]) = *(const int4*)(&Bt[(size_t)(colBase + r) * K + k0 + cc]);
    }
    __syncthreads();
    bf16x8 af[4], bfr[4];
#pragma unroll
    for (int i = 0; i < 4; ++i)
      af[i] = *(const bf16x8*)(&As[(wr + i * 16 + l16) * 32 + quad * 8]);
#pragma unroll
    for (int j = 0; j < 4; ++j)
      bfr[j] = *(const bf16x8*)(&Bs[(wc + j * 16 + l16) * 32 + quad * 8]);
#pragma unroll
    for (int i = 0; i < 4; ++i)
#pragma unroll
      for (int j = 0; j < 4; ++j)
        acc[i][j] = __builtin_amdgcn_mfma_f32_16x16x32_bf16(af[i], bfr[j], acc[i][j], 0, 0, 0);
  }

  const int isf = *flag;
  float bv[4];
#pragma unroll
  for (int j = 0; j < 4; ++j) bv[j] = ld_in(bias, colBase + wc + j * 16 + l16, isf);

#pragma unroll
  for (int i = 0; i < 4; ++i) {
    int row0 = rowBase + wr + i * 16 + quad * 4;   // chunk-local
#pragma unroll
    for (int j = 0; j < 4; ++j) {
      int col = colBase + wc + j * 16 + l16;
#pragma unroll
      for (int r = 0; r < 4; ++r) {
        int row = row0 + r;                        // chunk-local
        int grow = row + rowOff;                   // global
        float v = acc[i][j][r] + bv[j];
        if (EPI == 0) {
          v = fmaxf(v, 0.0f);
          outb[(size_t)row * N + col] = f2b(v);
        } else if (EPI == 1) {
          int b = grow >> 4, lr = grow & 15;
          outf[(size_t)b * 4096 + col * 16 + lr] = v;          // mu_logvar_2d (f32)
          if (col < 128) out1[(size_t)row * 160 + col] = f2b(v); // A3 mu part (bf16)
        } else {
          v = 1.0f / (1.0f + __expf(-v));
          int b = grow >> 4, l = grow & 15;
          int oh = l >> 2, ow = l & 3;
          int ch = col >> 8, kh = (col >> 4) & 15, kw = col & 15;
          outf[(size_t)b * 12288 + ch * 4096 + (oh * 16 + kh) * 64 + ow * 16 + kw] = v; // recon (f32)
        }
      }
    }
  }
}

// ---------------------------------------------------------------------------
// Workspace (u16 element offsets), R = chunk rows chosen to fit ws_size:
//   flag @ 0 (int, 2 u16 + 6 pad)
//   W1t  1024x800  @ 8
//   EW2t 256x1024  @ 8+819200
//   W3t  1024x160  @ +262144
//   DW2t 768x1024  @ +163840
//   A1c  Rx800     @ +786432   (=2031624)
//   hc   Rx1024    @ A1c + R*800
//   A3c  Rx160     @ hc + R*1024
// total bytes = 2*(2031624 + R*1984); R=4096 -> ~20.3MB, R=128 -> ~4.6MB
// ---------------------------------------------------------------------------

extern "C" void kernel_launch(void* const* d_in, const int* in_sizes, int n_in,
                              void* d_out, int out_size, void* d_ws, size_t ws_size,
                              hipStream_t stream) {
  const void* x   = d_in[0];
  const void* c   = d_in[1];
  const void* ew1 = d_in[2];
  const void* eb1 = d_in[3];
  const void* ew2 = d_in[4];
  const void* eb2 = d_in[5];
  const void* dw1 = d_in[6];
  const void* db1 = d_in[7];
  const void* dw2 = d_in[8];
  const void* db2 = d_in[9];
  float* out  = (float*)d_out;
  u16*   ws   = (u16*)d_ws;

  // adaptive chunk rows
  const size_t fixedU16 = 8 + 819200 + 262144 + 163840 + 786432;  // 2,031,624
  int R = 128;
  for (int cand = 4096; cand >= 128; cand >>= 1) {
    if ((fixedU16 + (size_t)cand * 1984) * 2 <= ws_size) { R = cand; break; }
  }

  int* flag = (int*)ws;
  u16* W1t  = ws + 8;
  u16* EW2t = W1t + 819200;
  u16* W3t  = EW2t + 262144;
  u16* DW2t = W3t + 163840;
  u16* A1c  = DW2t + 786432;
  u16* hc   = A1c + (size_t)R * 800;
  u16* A3c  = hc + (size_t)R * 1024;
  float* out2 = out + RECON_ELEMS;

  detect_f32<<<dim3(1), dim3(256), 0, stream>>>((const u16*)x, flag);

  transpose_pad<<<dim3((1024 * 800) / 256), dim3(256), 0, stream>>>(ew1, W1t, 1024, 800, 778, flag);
  transpose_pad<<<dim3((256 * 1024) / 256), dim3(256), 0, stream>>>(ew2, EW2t, 256, 1024, 1024, flag);
  transpose_pad<<<dim3((1024 * 160) / 256), dim3(256), 0, stream>>>(dw1, W3t, 1024, 160, 138, flag);
  transpose_pad<<<dim3((768 * 1024) / 256), dim3(256), 0, stream>>>(dw2, DW2t, 768, 1024, 1024, flag);

  const int chunks = 16384 / R;
  for (int chunk = 0; chunk < chunks; ++chunk) {
    int rowOff = chunk * R;
    build_a1<<<dim3((R * 100) / 256 + ((R * 100) % 256 ? 1 : 0)), dim3(256), 0, stream>>>(x, c, A1c, R, rowOff, flag);
    build_a3_tail<<<dim3((R * 32) / 256), dim3(256), 0, stream>>>(c, A3c, R, rowOff, flag);
    // enc1: h = relu(A1 @ W1 + b1), N=1024 K=800
    gemm_k<0><<<dim3(8, R / 128), dim3(256), 0, stream>>>(A1c, W1t, eb1, hc, nullptr, nullptr, 1024, 800, rowOff, flag);
    // enc2: mu_logvar = h @ W2 + b2, N=256 K=1024 (f32 scatter + A3 mu)
    gemm_k<1><<<dim3(2, R / 128), dim3(256), 0, stream>>>(hc, EW2t, eb2, nullptr, out2, A3c, 256, 1024, rowOff, flag);
    // dec1: hd = relu(A3 @ W3 + b3), N=1024 K=160
    gemm_k<0><<<dim3(8, R / 128), dim3(256), 0, stream>>>(A3c, W3t, db1, hc, nullptr, nullptr, 1024, 160, rowOff, flag);
    // dec2: recon = sigmoid(hd @ W4 + b4), N=768 K=1024 (f32 scatter)
    gemm_k<2><<<dim3(6, R / 128), dim3(256), 0, stream>>>(hc, DW2t, db2, nullptr, out, nullptr, 768, 1024, rowOff, flag);
  }
}

// Round 4
// 339.020 us; speedup vs baseline: 1.7774x; 1.7774x over previous
//
#include <hip/hip_runtime.h>

typedef unsigned short u16;
typedef unsigned int   u32;
typedef __bf16 bf16x8 __attribute__((ext_vector_type(8)));
typedef float  f32x4  __attribute__((ext_vector_type(4)));

__device__ __forceinline__ u16 f2b(float f) {
  u32 u = __builtin_bit_cast(u32, f);
  u = (u + 0x7fffu + ((u >> 16) & 1u)) >> 16;   // RNE
  return (u16)u;
}
__device__ __forceinline__ float b2f(u16 h) {
  u32 u = ((u32)h) << 16;
  return __builtin_bit_cast(float, u);
}
__device__ __forceinline__ float ld_in(const void* p, size_t idx, int isf32) {
  return isf32 ? ((const float*)p)[idx] : b2f(((const u16*)p)[idx]);
}
// async 16B global->LDS (wave-uniform LDS base + lane*16; our layout is
// chunk-contiguous so per-lane &lds[idx*8] matches HW semantics exactly)
__device__ __forceinline__ void async_cp16(const u16* g, u16* l) {
  __builtin_amdgcn_global_load_lds(
      (const __attribute__((address_space(1))) void*)g,
      (__attribute__((address_space(3))) void*)l, 16, 0, 0);
}

// Constants: BS=1024, CH=3, IMG=64, K=16, NC=10, HID=1024, LAT=128
// OH=4, L=16, PD=768, M=16384. Row-chunked; R adapts to ws_size (256MB -> 16384).
#define RECON_ELEMS 12582912   // 1024*3*64*64

// ---------------------------------------------------------------------------
// dtype detector: bf16 uniform[0,1) values are u16 in [0,0x3F80], sign=0.
// ---------------------------------------------------------------------------
__global__ __launch_bounds__(256) void detect_f32(const u16* __restrict__ x,
                                                  int* __restrict__ flag) {
  __shared__ int s;
  if (threadIdx.x == 0) s = 0;
  __syncthreads();
  int bad = 0;
  for (int i = threadIdx.x; i < 2048; i += 256) {
    u16 u = x[i];
    if ((u & 0x8000u) || (u > 0x3F80u)) bad = 1;
  }
  if (bad) atomicOr(&s, 1);
  __syncthreads();
  if (threadIdx.x == 0) *flag = s;
}

// ---------------------------------------------------------------------------
// A1 chunk (R x 800 bf16): [patch(768) | c(10) | zeros(22)]
// ---------------------------------------------------------------------------
__global__ __launch_bounds__(256) void build_a1(const void* __restrict__ x,
                                                const void* __restrict__ c,
                                                u16* __restrict__ A1,
                                                int R, int rowOff,
                                                const int* __restrict__ flag) {
  int g = blockIdx.x * 256 + threadIdx.x;          // R * 100 groups of 8 cols
  if (g >= R * 100) return;
  int row = g / 100, grp = g - row * 100;
  int grow = row + rowOff;
  int b = grow >> 4, l = grow & 15, oh = l >> 2, ow = l & 3;
  int isf = *flag;
  u16* dst = &A1[(size_t)row * 800 + grp * 8];
  int col0 = grp * 8;
  if (col0 < 768) {
    int ch = col0 >> 8, kh = (col0 >> 4) & 15, kw = col0 & 15;  // kw in {0,8}
    size_t off = (size_t)b * 12288 + ch * 4096 + (oh * 16 + kh) * 64 + ow * 16 + kw;
    if (isf) {
      const float* s = (const float*)x + off;
      float4 f0 = *(const float4*)(s);
      float4 f1 = *(const float4*)(s + 4);
      dst[0] = f2b(f0.x); dst[1] = f2b(f0.y); dst[2] = f2b(f0.z); dst[3] = f2b(f0.w);
      dst[4] = f2b(f1.x); dst[5] = f2b(f1.y); dst[6] = f2b(f1.z); dst[7] = f2b(f1.w);
    } else {
      *(int4*)dst = *(const int4*)((const u16*)x + off);
    }
  } else {
#pragma unroll
    for (int t = 0; t < 8; ++t) {
      int col = col0 + t;
      dst[t] = (col < 778) ? f2b(ld_in(c, (size_t)b * 10 + (col - 768), isf)) : (u16)0;
    }
  }
}

// ---------------------------------------------------------------------------
// Tiled transpose+pad: dst (N x Kpad) = src(Ksrc x N)^T, zero-pad k>=Ksrc.
// Both global sides coalesced via 32x32 LDS tile. Kpad, N multiples of 32.
// ---------------------------------------------------------------------------
__global__ __launch_bounds__(256) void transpose_pad(const void* __restrict__ src,
                                                     u16* __restrict__ dst,
                                                     int N, int Kpad, int Ksrc,
                                                     const int* __restrict__ flag) {
  __shared__ float t[32][33];
  const int tx = threadIdx.x & 31, ty = threadIdx.x >> 5;   // 32 x 8
  const int k0 = blockIdx.x * 32, n0 = blockIdx.y * 32;
  const int isf = *flag;
#pragma unroll
  for (int j = 0; j < 4; ++j) {
    int k = k0 + ty + j * 8;
    t[ty + j * 8][tx] = (k < Ksrc) ? ld_in(src, (size_t)k * N + n0 + tx, isf) : 0.0f;
  }
  __syncthreads();
#pragma unroll
  for (int j = 0; j < 4; ++j) {
    int n = n0 + ty + j * 8;
    dst[(size_t)n * Kpad + k0 + tx] = f2b(t[tx][ty + j * 8]);
  }
}

// A3 chunk tail cols 128..159: [c(10) | zeros(22)]
__global__ __launch_bounds__(256) void build_a3_tail(const void* __restrict__ c,
                                                     u16* __restrict__ A3,
                                                     int R, int rowOff,
                                                     const int* __restrict__ flag) {
  int i = blockIdx.x * 256 + threadIdx.x;          // R*32
  if (i >= R * 32) return;
  int row = i >> 5, col = 128 + (i & 31);
  int b = (row + rowOff) >> 4;
  int isf = *flag;
  A3[(size_t)row * 160 + col] = (col < 138) ? f2b(ld_in(c, (size_t)b * 10 + col - 128, isf)) : (u16)0;
}

// ---------------------------------------------------------------------------
// MFMA GEMM: C(R x N) = act(A(R x K) @ Bt(N x K)^T + bias)
// 128x128 tile, BK=32, 4 waves (2x2), each wave 4x4 16x16x32 MFMA tiles.
// Staging via global_load_lds width=16 (async, no VGPR round-trip).
// EPI: 0 = ReLU -> bf16 outb row-major (ld=N), chunk-local rows (internal h)
//      1 = none -> f32 outf = mu_logvar_2d scatter (global rows),
//                  bf16 out1 = A3 mu part (local, ld=160)
//      2 = sigmoid -> f32 outf = recon scatter (global rows)
// ---------------------------------------------------------------------------
template <int EPI>
__global__ __launch_bounds__(256) void gemm_k(const u16* __restrict__ A,
                                              const u16* __restrict__ Bt,
                                              const void* __restrict__ bias,
                                              u16* __restrict__ outb,
                                              float* __restrict__ outf,
                                              u16* __restrict__ out1,
                                              int N, int K, int rowOff,
                                              const int* __restrict__ flag) {
  __shared__ __align__(16) u16 As[128 * 32];
  __shared__ __align__(16) u16 Bs[128 * 32];
  const int tid  = threadIdx.x;
  const int lane = tid & 63;
  const int wave = tid >> 6;
  const int wr = (wave >> 1) * 64, wc = (wave & 1) * 64;
  const int quad = lane >> 4, l16 = lane & 15;
  const int rowBase = blockIdx.y * 128;
  const int colBase = blockIdx.x * 128;

  // per-thread staging chunk: idx in [0,512): r = idx>>2, cc = (idx&3)*8
  const int idx0 = tid, idx1 = 256 + tid;
  const int r0 = idx0 >> 2, c0 = (idx0 & 3) << 3;
  const int r1 = idx1 >> 2, c1 = (idx1 & 3) << 3;
  const u16* gA0 = &A[(size_t)(rowBase + r0) * K + c0];
  const u16* gA1 = &A[(size_t)(rowBase + r1) * K + c1];
  const u16* gB0 = &Bt[(size_t)(colBase + r0) * K + c0];
  const u16* gB1 = &Bt[(size_t)(colBase + r1) * K + c1];

  f32x4 acc[4][4] = {};

  for (int k0 = 0; k0 < K; k0 += 32) {
    __syncthreads();
    async_cp16(gA0 + k0, &As[idx0 * 8]);
    async_cp16(gA1 + k0, &As[idx1 * 8]);
    async_cp16(gB0 + k0, &Bs[idx0 * 8]);
    async_cp16(gB1 + k0, &Bs[idx1 * 8]);
    __syncthreads();
    bf16x8 af[4], bfr[4];
#pragma unroll
    for (int i = 0; i < 4; ++i)
      af[i] = *(const bf16x8*)(&As[(wr + i * 16 + l16) * 32 + quad * 8]);
#pragma unroll
    for (int j = 0; j < 4; ++j)
      bfr[j] = *(const bf16x8*)(&Bs[(wc + j * 16 + l16) * 32 + quad * 8]);
#pragma unroll
    for (int i = 0; i < 4; ++i)
#pragma unroll
      for (int j = 0; j < 4; ++j)
        acc[i][j] = __builtin_amdgcn_mfma_f32_16x16x32_bf16(af[i], bfr[j], acc[i][j], 0, 0, 0);
  }

  const int isf = *flag;
  float bv[4];
#pragma unroll
  for (int j = 0; j < 4; ++j) bv[j] = ld_in(bias, colBase + wc + j * 16 + l16, isf);

#pragma unroll
  for (int i = 0; i < 4; ++i) {
    int row0 = rowBase + wr + i * 16 + quad * 4;   // chunk-local
#pragma unroll
    for (int j = 0; j < 4; ++j) {
      int col = colBase + wc + j * 16 + l16;
#pragma unroll
      for (int r = 0; r < 4; ++r) {
        int row = row0 + r;                        // chunk-local
        int grow = row + rowOff;                   // global
        float v = acc[i][j][r] + bv[j];
        if (EPI == 0) {
          v = fmaxf(v, 0.0f);
          outb[(size_t)row * N + col] = f2b(v);
        } else if (EPI == 1) {
          int b = grow >> 4, lr = grow & 15;
          outf[(size_t)b * 4096 + col * 16 + lr] = v;            // mu_logvar_2d (f32)
          if (col < 128) out1[(size_t)row * 160 + col] = f2b(v);  // A3 mu (bf16)
        } else {
          v = 1.0f / (1.0f + __expf(-v));
          int b = grow >> 4, l = grow & 15;
          int oh = l >> 2, ow = l & 3;
          int ch = col >> 8, kh = (col >> 4) & 15, kw = col & 15;
          outf[(size_t)b * 12288 + ch * 4096 + (oh * 16 + kh) * 64 + ow * 16 + kw] = v;
        }
      }
    }
  }
}

// ---------------------------------------------------------------------------
// Workspace (u16 element offsets):
//   flag @ 0 (8 u16 incl pad) | W1t 1024x800 | EW2t 256x1024 | W3t 1024x160
//   DW2t 768x1024 | A1c Rx800 | hc Rx1024 | A3c Rx160
// bytes = 2*(2031624 + R*1984); R=16384 -> 69.1 MB (ws observed = 256 MB)
// ---------------------------------------------------------------------------

extern "C" void kernel_launch(void* const* d_in, const int* in_sizes, int n_in,
                              void* d_out, int out_size, void* d_ws, size_t ws_size,
                              hipStream_t stream) {
  const void* x   = d_in[0];
  const void* c   = d_in[1];
  const void* ew1 = d_in[2];
  const void* eb1 = d_in[3];
  const void* ew2 = d_in[4];
  const void* eb2 = d_in[5];
  const void* dw1 = d_in[6];
  const void* db1 = d_in[7];
  const void* dw2 = d_in[8];
  const void* db2 = d_in[9];
  float* out  = (float*)d_out;
  u16*   ws   = (u16*)d_ws;

  const size_t fixedU16 = 8 + 819200 + 262144 + 163840 + 786432;  // 2,031,624
  int R = 128;
  for (int cand = 16384; cand >= 128; cand >>= 1) {
    if ((fixedU16 + (size_t)cand * 1984) * 2 <= ws_size) { R = cand; break; }
  }

  int* flag = (int*)ws;
  u16* W1t  = ws + 8;
  u16* EW2t = W1t + 819200;
  u16* W3t  = EW2t + 262144;
  u16* DW2t = W3t + 163840;
  u16* A1c  = DW2t + 786432;
  u16* hc   = A1c + (size_t)R * 800;
  u16* A3c  = hc + (size_t)R * 1024;
  float* out2 = out + RECON_ELEMS;

  detect_f32<<<dim3(1), dim3(256), 0, stream>>>((const u16*)x, flag);

  transpose_pad<<<dim3(800 / 32, 1024 / 32), dim3(256), 0, stream>>>(ew1, W1t, 1024, 800, 778, flag);
  transpose_pad<<<dim3(1024 / 32, 256 / 32), dim3(256), 0, stream>>>(ew2, EW2t, 256, 1024, 1024, flag);
  transpose_pad<<<dim3(160 / 32, 1024 / 32), dim3(256), 0, stream>>>(dw1, W3t, 1024, 160, 138, flag);
  transpose_pad<<<dim3(1024 / 32, 768 / 32), dim3(256), 0, stream>>>(dw2, DW2t, 768, 1024, 1024, flag);

  const int chunks = 16384 / R;
  for (int chunk = 0; chunk < chunks; ++chunk) {
    int rowOff = chunk * R;
    build_a1<<<dim3((R * 100 + 255) / 256), dim3(256), 0, stream>>>(x, c, A1c, R, rowOff, flag);
    build_a3_tail<<<dim3((R * 32) / 256), dim3(256), 0, stream>>>(c, A3c, R, rowOff, flag);
    // enc1: h = relu(A1 @ W1 + b1), N=1024 K=800
    gemm_k<0><<<dim3(8, R / 128), dim3(256), 0, stream>>>(A1c, W1t, eb1, hc, nullptr, nullptr, 1024, 800, rowOff, flag);
    // enc2: mu_logvar = h @ W2 + b2, N=256 K=1024 (f32 scatter + A3 mu)
    gemm_k<1><<<dim3(2, R / 128), dim3(256), 0, stream>>>(hc, EW2t, eb2, nullptr, out2, A3c, 256, 1024, rowOff, flag);
    // dec1: hd = relu(A3 @ W3 + b3), N=1024 K=160
    gemm_k<0><<<dim3(8, R / 128), dim3(256), 0, stream>>>(A3c, W3t, db1, hc, nullptr, nullptr, 1024, 160, rowOff, flag);
    // dec2: recon = sigmoid(hd @ W4 + b4), N=768 K=1024 (f32 scatter)
    gemm_k<2><<<dim3(6, R / 128), dim3(256), 0, stream>>>(hc, DW2t, db2, nullptr, out, nullptr, 768, 1024, rowOff, flag);
  }
}

// Round 5
// 319.250 us; speedup vs baseline: 1.8875x; 1.0619x over previous
//
#include <hip/hip_runtime.h>

typedef unsigned short u16;
typedef unsigned int   u32;
typedef __bf16 bf16x8 __attribute__((ext_vector_type(8)));
typedef float  f32x4  __attribute__((ext_vector_type(4)));

__device__ __forceinline__ u16 f2b(float f) {
  u32 u = __builtin_bit_cast(u32, f);
  u = (u + 0x7fffu + ((u >> 16) & 1u)) >> 16;   // RNE
  return (u16)u;
}
__device__ __forceinline__ float b2f(u16 h) {
  u32 u = ((u32)h) << 16;
  return __builtin_bit_cast(float, u);
}
__device__ __forceinline__ float ld_in(const void* p, size_t idx, int isf32) {
  return isf32 ? ((const float*)p)[idx] : b2f(((const u16*)p)[idx]);
}
// async 16B global->LDS; HW semantics: LDS dest = wave-uniform base + lane*16
__device__ __forceinline__ void async_cp16(const u16* g, u16* l) {
  __builtin_amdgcn_global_load_lds(
      (const __attribute__((address_space(1))) void*)g,
      (__attribute__((address_space(3))) void*)l, 16, 0, 0);
}

// Constants: BS=1024, CH=3, IMG=64, K=16, NC=10, HID=1024, LAT=128
// OH=4, L=16, PD=768, M=16384. ws_size observed = 256MB -> single pass R=16384.
#define RECON_ELEMS 12582912   // 1024*3*64*64

// ---------------------------------------------------------------------------
// dtype detector: bf16 uniform[0,1) values are u16 in [0,0x3F80], sign=0.
// ---------------------------------------------------------------------------
__global__ __launch_bounds__(256) void detect_f32(const u16* __restrict__ x,
                                                  int* __restrict__ flag) {
  __shared__ int s;
  if (threadIdx.x == 0) s = 0;
  __syncthreads();
  int bad = 0;
  for (int i = threadIdx.x; i < 2048; i += 256) {
    u16 u = x[i];
    if ((u & 0x8000u) || (u > 0x3F80u)) bad = 1;
  }
  if (bad) atomicOr(&s, 1);
  __syncthreads();
  if (threadIdx.x == 0) *flag = s;
}

// ---------------------------------------------------------------------------
// A1 chunk (R x 800 bf16): [patch(768) | c(10) | zeros(22)]
// ---------------------------------------------------------------------------
__global__ __launch_bounds__(256) void build_a1(const void* __restrict__ x,
                                                const void* __restrict__ c,
                                                u16* __restrict__ A1,
                                                int R, int rowOff,
                                                const int* __restrict__ flag) {
  int g = blockIdx.x * 256 + threadIdx.x;          // R * 100 groups of 8 cols
  if (g >= R * 100) return;
  int row = g / 100, grp = g - row * 100;
  int grow = row + rowOff;
  int b = grow >> 4, l = grow & 15, oh = l >> 2, ow = l & 3;
  int isf = *flag;
  u16* dst = &A1[(size_t)row * 800 + grp * 8];
  int col0 = grp * 8;
  if (col0 < 768) {
    int ch = col0 >> 8, kh = (col0 >> 4) & 15, kw = col0 & 15;  // kw in {0,8}
    size_t off = (size_t)b * 12288 + ch * 4096 + (oh * 16 + kh) * 64 + ow * 16 + kw;
    if (isf) {
      const float* s = (const float*)x + off;
      float4 f0 = *(const float4*)(s);
      float4 f1 = *(const float4*)(s + 4);
      dst[0] = f2b(f0.x); dst[1] = f2b(f0.y); dst[2] = f2b(f0.z); dst[3] = f2b(f0.w);
      dst[4] = f2b(f1.x); dst[5] = f2b(f1.y); dst[6] = f2b(f1.z); dst[7] = f2b(f1.w);
    } else {
      *(int4*)dst = *(const int4*)((const u16*)x + off);
    }
  } else {
#pragma unroll
    for (int t = 0; t < 8; ++t) {
      int col = col0 + t;
      dst[t] = (col < 778) ? f2b(ld_in(c, (size_t)b * 10 + (col - 768), isf)) : (u16)0;
    }
  }
}

// ---------------------------------------------------------------------------
// Tiled transpose+pad: dst (N x Kpad) = src(Ksrc x N)^T, zero-pad k>=Ksrc.
// ---------------------------------------------------------------------------
__global__ __launch_bounds__(256) void transpose_pad(const void* __restrict__ src,
                                                     u16* __restrict__ dst,
                                                     int N, int Kpad, int Ksrc,
                                                     const int* __restrict__ flag) {
  __shared__ float t[32][33];
  const int tx = threadIdx.x & 31, ty = threadIdx.x >> 5;   // 32 x 8
  const int k0 = blockIdx.x * 32, n0 = blockIdx.y * 32;
  const int isf = *flag;
#pragma unroll
  for (int j = 0; j < 4; ++j) {
    int k = k0 + ty + j * 8;
    t[ty + j * 8][tx] = (k < Ksrc) ? ld_in(src, (size_t)k * N + n0 + tx, isf) : 0.0f;
  }
  __syncthreads();
#pragma unroll
  for (int j = 0; j < 4; ++j) {
    int n = n0 + ty + j * 8;
    dst[(size_t)n * Kpad + k0 + tx] = f2b(t[tx][ty + j * 8]);
  }
}

// A3 chunk tail cols 128..159: [c(10) | zeros(22)]
__global__ __launch_bounds__(256) void build_a3_tail(const void* __restrict__ c,
                                                     u16* __restrict__ A3,
                                                     int R, int rowOff,
                                                     const int* __restrict__ flag) {
  int i = blockIdx.x * 256 + threadIdx.x;          // R*32
  if (i >= R * 32) return;
  int row = i >> 5, col = 128 + (i & 31);
  int b = (row + rowOff) >> 4;
  int isf = *flag;
  A3[(size_t)row * 160 + col] = (col < 138) ? f2b(ld_in(c, (size_t)b * 10 + col - 128, isf)) : (u16)0;
}

// ---------------------------------------------------------------------------
// MFMA GEMM: C(R x N) = act(A(R x K) @ Bt(N x K)^T + bias)
// 128x128 tile, BK=32, 4 waves (2x2), 4x4 16x16x32 MFMA tiles per wave.
// 1D grid, by = bid % GY (GY%8==0 -> XCD = by%8): A-tile sharers colocate
// per XCD; B is L2-resident per XCD.
// LDS 16B XOR swizzle: slot s holds global chunk (r=s>>2, q=(s&3)^((s>>3)&3));
// read offset uses swq = quad ^ ((l16>>1)&3)  -> 2 lanes/bank-quad (free).
// EPI: 0 = ReLU -> bf16 outb row-major (ld=N)
//      1 = none -> f32 outf = mu_logvar_2d scatter, bf16 out1 = A3 mu (ld=160)
//      2 = sigmoid -> f32 outf = recon scatter
// ---------------------------------------------------------------------------
template <int EPI>
__global__ __launch_bounds__(256) void gemm_k(const u16* __restrict__ A,
                                              const u16* __restrict__ Bt,
                                              const void* __restrict__ bias,
                                              u16* __restrict__ outb,
                                              float* __restrict__ outf,
                                              u16* __restrict__ out1,
                                              int N, int K, int GY, int rowOff,
                                              const int* __restrict__ flag) {
  __shared__ __align__(16) u16 As[128 * 32];
  __shared__ __align__(16) u16 Bs[128 * 32];
  const int bid = blockIdx.x;
  const int by = bid % GY, bx = bid / GY;
  const int rowBase = by * 128, colBase = bx * 128;
  const int tid  = threadIdx.x;
  const int lane = tid & 63;
  const int wave = tid >> 6;
  const int wr = (wave >> 1) * 64, wc = (wave & 1) * 64;
  const int quad = lane >> 4, l16 = lane & 15;
  const int swq = quad ^ ((l16 >> 1) & 3);          // XOR-swizzled quad slot

  // staging: LDS slot s (= tid, tid+256) <- global chunk (r=s>>2, q=(s&3)^((s>>3)&3))
  const int s0 = tid, s1 = 256 + tid;
  const int r0 = s0 >> 2, q0 = (s0 & 3) ^ ((s0 >> 3) & 3);
  const int r1 = s1 >> 2, q1 = (s1 & 3) ^ ((s1 >> 3) & 3);
  const u16* gA0 = &A[(size_t)(rowBase + r0) * K + q0 * 8];
  const u16* gA1 = &A[(size_t)(rowBase + r1) * K + q1 * 8];
  const u16* gB0 = &Bt[(size_t)(colBase + r0) * K + q0 * 8];
  const u16* gB1 = &Bt[(size_t)(colBase + r1) * K + q1 * 8];

  f32x4 acc[4][4] = {};

  for (int k0 = 0; k0 < K; k0 += 32) {
    __syncthreads();
    async_cp16(gA0 + k0, &As[s0 * 8]);
    async_cp16(gA1 + k0, &As[s1 * 8]);
    async_cp16(gB0 + k0, &Bs[s0 * 8]);
    async_cp16(gB1 + k0, &Bs[s1 * 8]);
    __syncthreads();
    bf16x8 af[4], bfr[4];
#pragma unroll
    for (int i = 0; i < 4; ++i)
      af[i] = *(const bf16x8*)(&As[(wr + i * 16 + l16) * 32 + swq * 8]);
#pragma unroll
    for (int j = 0; j < 4; ++j)
      bfr[j] = *(const bf16x8*)(&Bs[(wc + j * 16 + l16) * 32 + swq * 8]);
#pragma unroll
    for (int i = 0; i < 4; ++i)
#pragma unroll
      for (int j = 0; j < 4; ++j)
        acc[i][j] = __builtin_amdgcn_mfma_f32_16x16x32_bf16(af[i], bfr[j], acc[i][j], 0, 0, 0);
  }

  const int isf = *flag;
  float bv[4];
#pragma unroll
  for (int j = 0; j < 4; ++j) bv[j] = ld_in(bias, colBase + wc + j * 16 + l16, isf);

#pragma unroll
  for (int i = 0; i < 4; ++i) {
    int row0 = rowBase + wr + i * 16 + quad * 4;   // chunk-local
#pragma unroll
    for (int j = 0; j < 4; ++j) {
      int col = colBase + wc + j * 16 + l16;
#pragma unroll
      for (int r = 0; r < 4; ++r) {
        int row = row0 + r;                        // chunk-local
        int grow = row + rowOff;                   // global
        float v = acc[i][j][r] + bv[j];
        if (EPI == 0) {
          v = fmaxf(v, 0.0f);
          outb[(size_t)row * N + col] = f2b(v);
        } else if (EPI == 1) {
          int b = grow >> 4, lr = grow & 15;
          outf[(size_t)b * 4096 + col * 16 + lr] = v;            // mu_logvar_2d (f32)
          if (col < 128) out1[(size_t)row * 160 + col] = f2b(v);  // A3 mu (bf16)
        } else {
          v = 1.0f / (1.0f + __expf(-v));
          int b = grow >> 4, l = grow & 15;
          int oh = l >> 2, ow = l & 3;
          int ch = col >> 8, kh = (col >> 4) & 15, kw = col & 15;
          outf[(size_t)b * 12288 + ch * 4096 + (oh * 16 + kh) * 64 + ow * 16 + kw] = v;
        }
      }
    }
  }
}

// ---------------------------------------------------------------------------
// Workspace (u16 element offsets):
//   flag @ 0 (8 u16 incl pad) | W1t 1024x800 | EW2t 256x1024 | W3t 1024x160
//   DW2t 768x1024 | A1c Rx800 | hc Rx1024 | A3c Rx160
// bytes = 2*(2031624 + R*1984); R=16384 -> 69.1 MB (ws observed = 256 MB)
// ---------------------------------------------------------------------------

extern "C" void kernel_launch(void* const* d_in, const int* in_sizes, int n_in,
                              void* d_out, int out_size, void* d_ws, size_t ws_size,
                              hipStream_t stream) {
  const void* x   = d_in[0];
  const void* c   = d_in[1];
  const void* ew1 = d_in[2];
  const void* eb1 = d_in[3];
  const void* ew2 = d_in[4];
  const void* eb2 = d_in[5];
  const void* dw1 = d_in[6];
  const void* db1 = d_in[7];
  const void* dw2 = d_in[8];
  const void* db2 = d_in[9];
  float* out  = (float*)d_out;
  u16*   ws   = (u16*)d_ws;

  const size_t fixedU16 = 8 + 819200 + 262144 + 163840 + 786432;  // 2,031,624
  int R = 128;
  for (int cand = 16384; cand >= 128; cand >>= 1) {
    if ((fixedU16 + (size_t)cand * 1984) * 2 <= ws_size) { R = cand; break; }
  }

  int* flag = (int*)ws;
  u16* W1t  = ws + 8;
  u16* EW2t = W1t + 819200;
  u16* W3t  = EW2t + 262144;
  u16* DW2t = W3t + 163840;
  u16* A1c  = DW2t + 786432;
  u16* hc   = A1c + (size_t)R * 800;
  u16* A3c  = hc + (size_t)R * 1024;
  float* out2 = out + RECON_ELEMS;

  detect_f32<<<dim3(1), dim3(256), 0, stream>>>((const u16*)x, flag);

  transpose_pad<<<dim3(800 / 32, 1024 / 32), dim3(256), 0, stream>>>(ew1, W1t, 1024, 800, 778, flag);
  transpose_pad<<<dim3(1024 / 32, 256 / 32), dim3(256), 0, stream>>>(ew2, EW2t, 256, 1024, 1024, flag);
  transpose_pad<<<dim3(160 / 32, 1024 / 32), dim3(256), 0, stream>>>(dw1, W3t, 1024, 160, 138, flag);
  transpose_pad<<<dim3(1024 / 32, 768 / 32), dim3(256), 0, stream>>>(dw2, DW2t, 768, 1024, 1024, flag);

  const int chunks = 16384 / R;
  const int GY = R / 128;
  for (int chunk = 0; chunk < chunks; ++chunk) {
    int rowOff = chunk * R;
    build_a1<<<dim3((R * 100 + 255) / 256), dim3(256), 0, stream>>>(x, c, A1c, R, rowOff, flag);
    build_a3_tail<<<dim3((R * 32) / 256), dim3(256), 0, stream>>>(c, A3c, R, rowOff, flag);
    // enc1: h = relu(A1 @ W1 + b1), N=1024 K=800
    gemm_k<0><<<dim3(8 * GY), dim3(256), 0, stream>>>(A1c, W1t, eb1, hc, nullptr, nullptr, 1024, 800, GY, rowOff, flag);
    // enc2: mu_logvar = h @ W2 + b2, N=256 K=1024 (f32 scatter + A3 mu)
    gemm_k<1><<<dim3(2 * GY), dim3(256), 0, stream>>>(hc, EW2t, eb2, nullptr, out2, A3c, 256, 1024, GY, rowOff, flag);
    // dec1: hd = relu(A3 @ W3 + b3), N=1024 K=160
    gemm_k<0><<<dim3(8 * GY), dim3(256), 0, stream>>>(A3c, W3t, db1, hc, nullptr, nullptr, 1024, 160, GY, rowOff, flag);
    // dec2: recon = sigmoid(hd @ W4 + b4), N=768 K=1024 (f32 scatter)
    gemm_k<2><<<dim3(6 * GY), dim3(256), 0, stream>>>(hc, DW2t, db2, nullptr, out, nullptr, 768, 1024, GY, rowOff, flag);
  }
}